// Round 1
// 113.649 us; speedup vs baseline: 1.0020x; 1.0020x over previous
//
#include <hip/hip_runtime.h>

// Edge dot-product: score[e] = dot(h[src[e]], h[dst[e]]), D=128.
// R4: miss-path (L2<->LLC fabric) ceiling; int8 rows = 128 B = one L2 line.
// R5 (this round): edge kernel was mixed instruction-bound (20 shfl + ~65
// wave-instrs per 8 edges) on top of the ~23us fabric floor. Restructure to
// 8-lanes-per-edge: int4 (16B) loads, v_dot4_i32_i8 in-lane partials, 3-step
// shfl reduce shared by all edges of the wave. Same 2 line-requests/edge.
//   score = s_a * s_b * sum_i(qa_i * qb_i)
// Error: absmax ~0.55 vs threshold 3.26 (unchanged quantization).

#define D_FEAT 128
#define BLOCK 256
#define GROUPS_PER_BLOCK (BLOCK / 32)   // 8 groups of 32 lanes
#define EPG 4                           // edges per 32-lane group (8 lanes/edge)

#if defined(__has_builtin)
#if __has_builtin(__builtin_amdgcn_sdot4)
#define HAVE_SDOT4 1
#endif
#endif

#ifdef HAVE_SDOT4
#define DOT4(a, b, c) __builtin_amdgcn_sdot4((a), (b), (c), false)
#else
static __device__ __forceinline__ int DOT4(int a, int b, int c) {
    const char4 av = *(const char4*)&a;
    const char4 bv = *(const char4*)&b;
    return c + (int)av.x * bv.x + (int)av.y * bv.y
             + (int)av.z * bv.z + (int)av.w * bv.w;
}
#endif

// ---- pass 1: per-row int8 quantization ----
// one 32-lane group per node row; lane loads float4 (row = 32*4 elems),
// shfl-max for rowmax, quantize, write char4 (coalesced 128 B/row).
__global__ __launch_bounds__(BLOCK) void quant_kernel(
    const float* __restrict__ h,
    char* __restrict__ qtab,
    float* __restrict__ scales,
    int n_nodes)
{
    const int group = threadIdx.x >> 5;
    const int lane  = threadIdx.x & 31;
    const int node  = blockIdx.x * GROUPS_PER_BLOCK + group;
    if (node >= n_nodes) return;

    const float4 v = ((const float4*)(h + (long long)node * D_FEAT))[lane];

    float m = fmaxf(fmaxf(fabsf(v.x), fabsf(v.y)), fmaxf(fabsf(v.z), fabsf(v.w)));
    #pragma unroll
    for (int off = 16; off >= 1; off >>= 1)
        m = fmaxf(m, __shfl_xor(m, off));

    const float inv = (m > 0.0f) ? (127.0f / m) : 0.0f;
    const float s   = (m > 0.0f) ? (m / 127.0f) : 0.0f;

    char4 q;
    q.x = (char)__float2int_rn(v.x * inv);
    q.y = (char)__float2int_rn(v.y * inv);
    q.z = (char)__float2int_rn(v.z * inv);
    q.w = (char)__float2int_rn(v.w * inv);
    ((char4*)(qtab + (long long)node * D_FEAT))[lane] = q;

    if (lane == 0) scales[node] = s;
}

// ---- pass 2: int8 gather-dot, 8 lanes per edge ----
// lane = (edge j = lane>>3, chunk c = lane&7). Each lane loads int4 (16 B)
// of the src row and dst row: per row exactly one 128-B line request.
// In-lane 16-elem dot via 4x sdot4; 3-step shfl_xor reduce within 8 lanes.
__global__ __launch_bounds__(BLOCK) void edge_dot_q8_kernel(
    const char* __restrict__ qtab,
    const float* __restrict__ scales,
    const int* __restrict__ src,
    const int* __restrict__ dst,
    float* __restrict__ out,
    int n_edges)
{
    const int tgroup = threadIdx.x >> 5;          // 32-lane group in block
    const int lane   = threadIdx.x & 31;
    const int j      = lane >> 3;                 // edge within group [0,4)
    const int c      = lane & 7;                  // 16-B chunk within row [0,8)

    const int g  = blockIdx.x * GROUPS_PER_BLOCK + tgroup;
    const int e  = g * EPG + j;
    const bool valid = (e < n_edges);

    // broadcast loads: 8 lanes share each address -> 1 request per 16 B
    const int sv = valid ? src[e] : 0;
    const int dv = valid ? dst[e] : 0;

    const int4 a = ((const int4*)(qtab + (long long)sv * D_FEAT))[c];
    const int4 b = ((const int4*)(qtab + (long long)dv * D_FEAT))[c];

    int p = DOT4(a.x, b.x, 0);
    p = DOT4(a.y, b.y, p);
    p = DOT4(a.z, b.z, p);
    p = DOT4(a.w, b.w, p);

    // reduce within the 8-lane team (masks stay inside the team)
    p += __shfl_xor(p, 4);
    p += __shfl_xor(p, 2);
    p += __shfl_xor(p, 1);

    if (c == 0 && valid) {
        const float ss = scales[sv] * scales[dv];
        out[e] = (float)p * ss;   // lanes 0,8,16,24: 4 consecutive floats
    }
}

// ---- fp32 fallback (R2 path) if ws too small ----
__global__ __launch_bounds__(BLOCK) void edge_dot_f32_kernel(
    const float* __restrict__ h,
    const int* __restrict__ src,
    const int* __restrict__ dst,
    float* __restrict__ out,
    int n_edges)
{
    const int group = threadIdx.x >> 5;
    const int lane  = threadIdx.x & 31;
    const int g  = blockIdx.x * GROUPS_PER_BLOCK + group;
    const int e0 = g * EPG;
    if (e0 >= n_edges) return;
    const int eend = min(e0 + EPG, n_edges);
    for (int e = e0; e < eend; ++e) {
        const float4 a = ((const float4*)(h + (long long)src[e] * D_FEAT))[lane];
        const float4 b = ((const float4*)(h + (long long)dst[e] * D_FEAT))[lane];
        float p = a.x * b.x + a.y * b.y + a.z * b.z + a.w * b.w;
        #pragma unroll
        for (int off = 16; off >= 1; off >>= 1)
            p += __shfl_xor(p, off);
        if (lane == 0) out[e] = p;
    }
}

extern "C" void kernel_launch(void* const* d_in, const int* in_sizes, int n_in,
                              void* d_out, int out_size, void* d_ws, size_t ws_size,
                              hipStream_t stream) {
    const float* h   = (const float*)d_in[0];
    const int*   src = (const int*)d_in[1];
    const int*   dst = (const int*)d_in[2];
    float*       out = (float*)d_out;

    const int n_elems = in_sizes[0];           // N_NODES * D_FEAT
    const int n_nodes = n_elems / D_FEAT;      // 100000
    const int n_edges = in_sizes[1];           // 640000

    const size_t scale_bytes = ((size_t)n_nodes * 4 + 255) & ~(size_t)255;
    const size_t need = scale_bytes + (size_t)n_nodes * D_FEAT;

    if (ws_size >= need) {
        float* scales = (float*)d_ws;
        char*  qtab   = (char*)d_ws + scale_bytes;

        const int qgrid = (n_nodes + GROUPS_PER_BLOCK - 1) / GROUPS_PER_BLOCK;
        quant_kernel<<<qgrid, BLOCK, 0, stream>>>(h, qtab, scales, n_nodes);

        const int edges_per_block = GROUPS_PER_BLOCK * EPG;   // 32
        const int grid = (n_edges + edges_per_block - 1) / edges_per_block;
        edge_dot_q8_kernel<<<grid, BLOCK, 0, stream>>>(qtab, scales, src, dst,
                                                       out, n_edges);
    } else {
        const int n_groups = (n_edges + EPG - 1) / EPG;
        const int grid = (n_groups + GROUPS_PER_BLOCK - 1) / GROUPS_PER_BLOCK;
        edge_dot_f32_kernel<<<grid, BLOCK, 0, stream>>>(h, src, dst, out, n_edges);
    }
}